// Round 14
// baseline (769.987 us; speedup 1.0000x reference)
//
#include <hip/hip_runtime.h>
#include <hip/hip_bf16.h>

#define NN 40000
#define EE 400000

typedef short short8 __attribute__((ext_vector_type(8)));
typedef float f32x4 __attribute__((ext_vector_type(4)));
typedef unsigned short ushort4_ __attribute__((ext_vector_type(4)));
typedef unsigned int uint4_ __attribute__((ext_vector_type(4)));

__device__ __forceinline__ unsigned short f2bf(float f) {
  unsigned int u = __float_as_uint(f);
  u = (u + 0x7FFFu + ((u >> 16) & 1u)) >> 16;
  return (unsigned short)u;
}

// packed f32->bf16 (RNE) — compiler emits v_cvt_pk_bf16_f32
__device__ __forceinline__ unsigned cvtpk(float lo, float hi) {
  __hip_bfloat162 t = __float22bfloat162_rn(float2{lo, hi});
  return *reinterpret_cast<unsigned*>(&t);
}

__device__ __forceinline__ short8 cvt8(f32x4 a, f32x4 b) {
  uint4_ u;
  u[0] = cvtpk(a[0], a[1]);
  u[1] = cvtpk(a[2], a[3]);
  u[2] = cvtpk(b[0], b[1]);
  u[3] = cvtpk(b[2], b[3]);
  return *reinterpret_cast<short8*>(&u);
}

__device__ __forceinline__ f32x4 ld_bf4(const unsigned short* p) {
  ushort4_ u = *(const ushort4_*)p;
  f32x4 r;
  r[0] = __uint_as_float((unsigned int)u[0] << 16);
  r[1] = __uint_as_float((unsigned int)u[1] << 16);
  r[2] = __uint_as_float((unsigned int)u[2] << 16);
  r[3] = __uint_as_float((unsigned int)u[3] << 16);
  return r;
}

__device__ __forceinline__ float lrelu(float v) { return v >= 0.f ? v : 0.2f * v; }

// monotone float<->uint encoding for atomicMax on floats
__device__ __forceinline__ unsigned fenc(float f) {
  unsigned b = __float_as_uint(f);
  return (b & 0x80000000u) ? ~b : (b | 0x80000000u);
}
__device__ __forceinline__ float fdec(unsigned e) {
  return __uint_as_float((e >> 31) ? (e & 0x7fffffffu) : ~e);
}

#define PREP_N 278528  // 262144 wt2 + 16384 weffb

// ---- fused prep + edge histogram ------------------------------------------
__global__ __launch_bounds__(256) void k_prephist(
    const float* __restrict__ W, const float* __restrict__ asrc,
    const float* __restrict__ adst,
    const int* __restrict__ e0, const int* __restrict__ e1,
    const int* __restrict__ e2, const int* __restrict__ e3,
    unsigned short* __restrict__ wt2, unsigned short* __restrict__ weffb,
    int* __restrict__ cnt) {
  int idx = blockIdx.x * 256 + threadIdx.x;
  if (idx < 262144) {
    int k0 = idx & 31, n = (idx >> 5) & 255, kt = (idx >> 13) & 7, r = idx >> 16;
    int cp = k0 >> 3, e = k0 & 7;
    int k0s = ((cp ^ ((n >> 1) & 3)) << 3) | e;
    wt2[idx] = f2bf(W[((size_t)(r * 256) + (kt * 32 + k0s)) * 256 + n]);
  } else if (idx < PREP_N) {
    int id2 = idx - 262144;
    int k0 = id2 & 31, col = (id2 >> 5) & 63, kt = id2 >> 11;
    int q = col >> 3, j = col & 7;
    int r = q >> 1, side = q & 1;
    int f = kt * 32 + k0;
    const float* att = side ? adst : asrc;
    const float* wrow = W + ((size_t)(r * 256) + f) * 256 + j * 32;
    const float* arow = att + (r * 8 + j) * 32;
    float s = 0.f;
#pragma unroll
    for (int c = 0; c < 32; ++c) s += wrow[c] * arow[c];
    weffb[id2] = f2bf(s);
  } else {
    int e = idx - PREP_N;
    if (e < 4 * EE) {
      int r = e / EE;
      int ee = e - r * EE;
      const int* ei = (r == 0) ? e0 : (r == 1) ? e1 : (r == 2) ? e2 : e3;
      atomicAdd(&cnt[r * NN + ei[EE + ee]], 1);
    }
  }
}

__global__ __launch_bounds__(1024) void k_scan(const int* __restrict__ cnt,
                                               int* __restrict__ rowptr,
                                               int* __restrict__ cursor) {
  int r = blockIdx.x;
  const int* c = cnt + r * NN;
  int* rp = rowptr + r * (NN + 1);
  int* cur = cursor + r * NN;
  __shared__ int part[1024];
  int t = threadIdx.x;
  const int per = 40;  // 1024*40 >= 40000
  int base = t * per;
  int sum = 0;
  for (int i = 0; i < per; ++i) { int idx = base + i; if (idx < NN) sum += c[idx]; }
  part[t] = sum;
  __syncthreads();
  for (int o = 1; o < 1024; o <<= 1) {
    int v = (t >= o) ? part[t - o] : 0;
    __syncthreads();
    part[t] += v;
    __syncthreads();
  }
  int run = part[t] - sum;  // exclusive prefix
  for (int i = 0; i < per; ++i) {
    int idx = base + i;
    if (idx < NN) { rp[idx] = run; cur[idx] = run; run += c[idx]; }
  }
  if (t == 1023) rp[NN] = part[1023];
}

// ---- fused scatter (blocks 0..6249) + GEMM (blocks 6250..11249) -----------
// GEMM: hbi[r][n][g][256] = bf16(x @ W), BK=32 double-buffered (1 barrier/kt)
#define SCAT_BLOCKS 6250
__global__ __launch_bounds__(256) void k_scatgemm(
    const int* __restrict__ e0, const int* __restrict__ e1,
    const int* __restrict__ e2, const int* __restrict__ e3,
    int* __restrict__ cursor, int* __restrict__ adj,
    const float* __restrict__ x0, const float* __restrict__ x1, const float* __restrict__ x2,
    const float* __restrict__ x3, const float* __restrict__ x4, const float* __restrict__ x5,
    const unsigned short* __restrict__ wt2, const unsigned short* __restrict__ weffb,
    unsigned short* __restrict__ hbi, float* __restrict__ alpf,
    unsigned* __restrict__ maxsrcE) {
  __shared__ __attribute__((aligned(16))) unsigned short Abuf[2][64][40];
  __shared__ __attribute__((aligned(16))) unsigned short Bbuf[2][256][32];
  if (blockIdx.x < SCAT_BLOCKS) {
    int e = blockIdx.x * 256 + threadIdx.x;
    if (e < 4 * EE) {
      int r = e / EE;
      int ee = e - r * EE;
      const int* ei = (r == 0) ? e0 : (r == 1) ? e1 : (r == 2) ? e2 : e3;
      int s = ei[ee], d = ei[EE + ee];
      int pos = atomicAdd(&cursor[r * NN + d], 1);
      adj[(size_t)r * EE + pos] = s;
    }
    return;
  }
  int bid = blockIdx.x - SCAT_BLOCKS;
  int y = bid / 625, bx = bid - y * 625;  // y = g*4 + r
  const int srct[4] = {0, 1, 0, 2};
  int g = y >> 2, r = y & 3;
  int ty = srct[r];
  int t6 = g * 3 + ty;
  const float* xp;
  switch (t6) { case 0: xp = x0; break; case 1: xp = x1; break; case 2: xp = x2; break;
                case 3: xp = x3; break; case 4: xp = x4; break; default: xp = x5; break; }
  const unsigned short* wtp = wt2 + (size_t)r * (8 * 256 * 32);
  int tid = threadIdx.x;
  int wave = tid >> 6, lane = tid & 63;
  int l15 = lane & 15, l16 = lane >> 4;
  int row0 = bx * 64;
  f32x4 acc[4][4] = {};
  f32x4 lacc[4] = {};
  bool dolog = (r != 2);
  int lcol = wave * 16 + l15;
  int ar = tid >> 2, ac = (tid & 3) * 8;  // 8 floats per thread per kt
  const float* aglob = xp + (size_t)(row0 + ar) * 256 + ac;
  unsigned short* lB0 = &Bbuf[0][0][0];
  unsigned short* lB1 = &Bbuf[1][0][0];
  {
    f32x4 a0 = *(const f32x4*)(aglob);
    f32x4 a1 = *(const f32x4*)(aglob + 4);
    *(short8*)(&Abuf[0][ar][ac]) = cvt8(a0, a1);
#pragma unroll
    for (int i = 0; i < 4; ++i) {
      int gofs = (tid + 256 * i) * 8;
      int lofs = (wave * 64 + i * 256) * 8;
      __builtin_amdgcn_global_load_lds(
          (const __attribute__((address_space(1))) void*)(wtp + gofs),
          (__attribute__((address_space(3))) void*)(lB0 + lofs), 16, 0, 0);
    }
  }
  __syncthreads();
  for (int kt = 0; kt < 8; ++kt) {
    int cur = kt & 1;
    unsigned short* lBn = cur ? lB0 : lB1;
    f32x4 a0, a1;
    if (kt < 7) {
      const unsigned short* bn = wtp + (kt + 1) * 8192;
#pragma unroll
      for (int i = 0; i < 4; ++i) {
        int gofs = (tid + 256 * i) * 8;
        int lofs = (wave * 64 + i * 256) * 8;
        __builtin_amdgcn_global_load_lds(
            (const __attribute__((address_space(1))) void*)(bn + gofs),
            (__attribute__((address_space(3))) void*)(lBn + lofs), 16, 0, 0);
      }
      a0 = *(const f32x4*)(aglob + (kt + 1) * 32);
      a1 = *(const f32x4*)(aglob + (kt + 1) * 32 + 4);
    }
    short8 af[4], bf[4];
#pragma unroll
    for (int mt = 0; mt < 4; ++mt)
      af[mt] = *(const short8*)(&Abuf[cur][mt * 16 + l15][l16 * 8]);
#pragma unroll
    for (int nt = 0; nt < 4; ++nt) {
      int sn = wave * 64 + nt * 16 + l15;
      int cs = (l16 ^ ((sn >> 1) & 3)) * 8;  // bank swizzle (matches wt2)
      bf[nt] = *(const short8*)(&Bbuf[cur][sn][cs]);
    }
#pragma unroll
    for (int mt = 0; mt < 4; ++mt)
#pragma unroll
      for (int nt = 0; nt < 4; ++nt)
        acc[mt][nt] = __builtin_amdgcn_mfma_f32_16x16x32_bf16(af[mt], bf[nt], acc[mt][nt], 0, 0, 0);
    if (dolog) {
      short8 lb = *(const short8*)(weffb + kt * 2048 + lcol * 32 + l16 * 8);
#pragma unroll
      for (int mt = 0; mt < 4; ++mt)
        lacc[mt] = __builtin_amdgcn_mfma_f32_16x16x32_bf16(af[mt], lb, lacc[mt], 0, 0, 0);
    }
    if (kt < 7) *(short8*)(&Abuf[cur ^ 1][ar][ac]) = cvt8(a0, a1);
    __syncthreads();
  }
#pragma unroll
  for (int mt = 0; mt < 4; ++mt)
#pragma unroll
    for (int nt = 0; nt < 4; ++nt)
#pragma unroll
      for (int rr = 0; rr < 4; ++rr) {
        int row = row0 + mt * 16 + l16 * 4 + rr;
        hbi[((size_t)(r * NN + row) * 2 + g) * 256 + wave * 64 + nt * 16 + l15] =
            f2bf(acc[mt][nt][rr]);
      }
  if (dolog) {
    int q = lcol >> 3, jj = lcol & 7;
#pragma unroll
    for (int mt = 0; mt < 4; ++mt)
#pragma unroll
      for (int rr = 0; rr < 4; ++rr) {
        int row = row0 + mt * 16 + l16 * 4 + rr;
        alpf[((size_t)(ty * 8 + q) * NN + row) * 16 + jj * 2 + g] = lacc[mt][rr];
      }
    if ((q & 1) == 0 && srct[q >> 1] == ty) {
      float m = -1e30f;
#pragma unroll
      for (int mt = 0; mt < 4; ++mt)
#pragma unroll
        for (int rr = 0; rr < 4; ++rr) m = fmaxf(m, lacc[mt][rr]);
      m = fmaxf(m, __shfl_xor(m, 16, 64));
      m = fmaxf(m, __shfl_xor(m, 32, 64));
      if (l16 == 0) atomicMax(maxsrcE + (g * 4 + (q >> 1)) * 8 + jj, fenc(m));
    }
  }
}

// ---- one-relation aggregation for BOTH graphs, 8-edge groups --------------
__device__ __forceinline__ void agg_one2(
    int r, int d, int lane,
    const int* __restrict__ rowptr4, const int* __restrict__ adj4,
    const float* __restrict__ alpf, const unsigned short* __restrict__ hbi,
    const unsigned* __restrict__ maxsrcE, f32x4& o0, f32x4& o1) {
  const int srct[4] = {0, 1, 0, 2};
  const int dstt[4] = {1, 0, 2, 0};
  int h = lane >> 3, e8 = lane & 7, ob = lane & 56;
  const int* rowptr = rowptr4 + r * (NN + 1);
  const int* adj = adj4 + (size_t)r * EE;
  const float* asb = alpf + ((size_t)(srct[r] * 8 + 2 * r) * NN) * 16;
  const float* adb = alpf + ((size_t)(dstt[r] * 8 + 2 * r + 1) * NN) * 16;
  const unsigned short* hbr = hbi + (size_t)(r * NN) * 512;

  int beg = rowptr[d], end = rowptr[d + 1];
  float2 adp = *(const float2*)(adb + (size_t)d * 16 + h * 2);
  float adst0 = adp.x, adst1 = adp.y;
  float ub0 = lrelu(fdec(maxsrcE[r * 8 + h]) + adst0);
  float ub1 = lrelu(fdec(maxsrcE[(4 + r) * 8 + h]) + adst1);
  float2 asp = *(const float2*)(asb + (size_t)d * 16 + h * 2);
  float ws0 = __expf(lrelu(asp.x + adst0) - ub0);
  float ws1 = __expf(lrelu(asp.y + adst1) - ub1);
  float ssum0 = (e8 == 0) ? ws0 : 0.0f;
  float ssum1 = (e8 == 0) ? ws1 : 0.0f;
  const unsigned short* selfrow = hbr + (size_t)d * 512;
  f32x4 hv0 = ld_bf4(selfrow + lane * 4);
  f32x4 hv1 = ld_bf4(selfrow + 256 + lane * 4);
  f32x4 acc0, acc1;
#pragma unroll
  for (int i = 0; i < 4; ++i) { acc0[i] = ws0 * hv0[i]; acc1[i] = ws1 * hv1[i]; }

  for (int j0 = beg; j0 < end; j0 += 8) {
    int j = j0 + e8;
    bool valid = j < end;
    int s = valid ? adj[j] : d;
    float2 lp = *(const float2*)(asb + (size_t)s * 16 + h * 2);
    float w0 = valid ? __expf(lrelu(lp.x + adst0) - ub0) : 0.f;
    float w1 = valid ? __expf(lrelu(lp.y + adst1) - ub1) : 0.f;
    ssum0 += w0;
    ssum1 += w1;
#pragma unroll
    for (int e2 = 0; e2 < 8; ++e2) {
      int se = __shfl(s, ob + e2, 64);
      float w0e = __shfl(w0, ob + e2, 64);
      float w1e = __shfl(w1, ob + e2, 64);
      const unsigned short* row = hbr + (size_t)se * 512;
      f32x4 g0 = ld_bf4(row + lane * 4);
      f32x4 g1 = ld_bf4(row + 256 + lane * 4);
#pragma unroll
      for (int i = 0; i < 4; ++i) { acc0[i] += w0e * g0[i]; acc1[i] += w1e * g1[i]; }
    }
  }
  ssum0 += __shfl_xor(ssum0, 1, 64);
  ssum0 += __shfl_xor(ssum0, 2, 64);
  ssum0 += __shfl_xor(ssum0, 4, 64);
  ssum1 += __shfl_xor(ssum1, 1, 64);
  ssum1 += __shfl_xor(ssum1, 2, 64);
  ssum1 += __shfl_xor(ssum1, 4, 64);
  float i0 = 1.f / ssum0, i1 = 1.f / ssum1;
#pragma unroll
  for (int i = 0; i < 4; ++i) { o0[i] = acc0[i] * i0; o1[i] = acc1[i] * i1; }
}

// ---- persistent-wave aggregation, both graphs per item --------------------
#define AGG_BLOCKS 1875
__global__ __launch_bounds__(256) void k_agg6(
    const int* __restrict__ rowptr4, const int* __restrict__ adj4,
    const float* __restrict__ alpf, const unsigned short* __restrict__ hbi,
    const float* __restrict__ bias, const unsigned* __restrict__ maxsrcE,
    float* __restrict__ out) {
  int lane = threadIdx.x & 63;
  int wgid = (blockIdx.x * 256 + (int)threadIdx.x) >> 6;
  const int NWV = AGG_BLOCKS * 4;
  for (int item = wgid; item < 3 * NN; item += NWV) {
    int y = item / NN;
    int d = item - y * NN;
    f32x4 r0g0, r0g1, r1g0, r1g1;
    int sec;
    if (y == 1) {
      agg_one2(1, d, lane, rowptr4, adj4, alpf, hbi, maxsrcE, r0g0, r0g1);
      agg_one2(3, d, lane, rowptr4, adj4, alpf, hbi, maxsrcE, r1g0, r1g1);
      f32x4 b1 = *(const f32x4*)(bias + 1 * 256 + lane * 4);
      f32x4 b3 = *(const f32x4*)(bias + 3 * 256 + lane * 4);
#pragma unroll
      for (int i = 0; i < 4; ++i) {
        r0g0[i] = 0.5f * (r0g0[i] + b1[i] + r1g0[i] + b3[i]);
        r0g1[i] = 0.5f * (r0g1[i] + b1[i] + r1g1[i] + b3[i]);
      }
      sec = 0;
    } else {
      int r = (y == 0) ? 0 : 2;
      agg_one2(r, d, lane, rowptr4, adj4, alpf, hbi, maxsrcE, r0g0, r0g1);
      f32x4 bv = *(const f32x4*)(bias + r * 256 + lane * 4);
#pragma unroll
      for (int i = 0; i < 4; ++i) { r0g0[i] += bv[i]; r0g1[i] += bv[i]; }
      sec = (y == 0) ? 1 : 2;
    }
    f32x4* op0 = (f32x4*)(out + ((size_t)(0 + sec) * NN + d) * 256 + lane * 4);
    f32x4* op1 = (f32x4*)(out + ((size_t)(3 + sec) * NN + d) * 256 + lane * 4);
    __builtin_nontemporal_store(r0g0, op0);
    __builtin_nontemporal_store(r0g1, op1);
  }
}

extern "C" void kernel_launch(void* const* d_in, const int* in_sizes, int n_in,
                              void* d_out, int out_size, void* d_ws, size_t ws_size,
                              hipStream_t stream) {
  (void)in_sizes; (void)n_in; (void)out_size; (void)ws_size;
  const float* x[6];
  for (int i = 0; i < 6; ++i) x[i] = (const float*)d_in[i];
  const float* W = (const float*)d_in[6];
  const float* att_src = (const float*)d_in[7];
  const float* att_dst = (const float*)d_in[8];
  const float* bias = (const float*)d_in[9];
  const int* ei[4] = {(const int*)d_in[10], (const int*)d_in[11],
                      (const int*)d_in[12], (const int*)d_in[13]};
  float* out = (float*)d_out;

  char* ws = (char*)d_ws;
  size_t off = 0;
  auto take = [&](size_t bytes) -> char* {
    char* p = ws + off;
    off += (bytes + 255) & ~(size_t)255;
    return p;
  };
  unsigned short* hbi = (unsigned short*)take(8ull * NN * 256 * 2);   // 163.8 MB
  float* alpf = (float*)take(3ull * 8 * NN * 16 * 4);                 // 61.4 MB
  unsigned short* wt2 = (unsigned short*)take(4ull * 8 * 256 * 32 * 2);
  unsigned short* weffb = (unsigned short*)take(8ull * 64 * 32 * 2);
  int* cnt = (int*)take(4ull * NN * 4);            // 640000 B (multiple of 256)
  unsigned* maxsrcE = (unsigned*)take(64ull * 4);  // contiguous after cnt
  int* rowptr = (int*)take(4ull * (NN + 1) * 4);
  int* cursor = (int*)take(4ull * NN * 4);
  int* adj = (int*)take(4ull * EE * 4);

  hipMemsetAsync(cnt, 0, 4ull * NN * 4 + 256, stream);  // zeroes cnt + maxsrcE
  k_prephist<<<dim3((PREP_N + 4 * EE + 255) / 256), 256, 0, stream>>>(
      W, att_src, att_dst, ei[0], ei[1], ei[2], ei[3], wt2, weffb, cnt);
  k_scan<<<dim3(4), 1024, 0, stream>>>(cnt, rowptr, cursor);
  k_scatgemm<<<dim3(SCAT_BLOCKS + 5000), 256, 0, stream>>>(
      ei[0], ei[1], ei[2], ei[3], cursor, adj,
      x[0], x[1], x[2], x[3], x[4], x[5], wt2, weffb, hbi, alpf, maxsrcE);
  k_agg6<<<dim3(AGG_BLOCKS), 256, 0, stream>>>(rowptr, adj, alpf, hbi, bias, maxsrcE, out);
}

// Round 15
// 756.241 us; speedup vs baseline: 1.0182x; 1.0182x over previous
//
#include <hip/hip_runtime.h>
#include <hip/hip_bf16.h>

#define NN 40000
#define EE 400000

typedef short short8 __attribute__((ext_vector_type(8)));
typedef float f32x4 __attribute__((ext_vector_type(4)));
typedef unsigned short ushort4_ __attribute__((ext_vector_type(4)));
typedef unsigned int uint4_ __attribute__((ext_vector_type(4)));

__device__ __forceinline__ unsigned short f2bf(float f) {
  unsigned int u = __float_as_uint(f);
  u = (u + 0x7FFFu + ((u >> 16) & 1u)) >> 16;
  return (unsigned short)u;
}

// packed f32->bf16 (RNE) — compiler emits v_cvt_pk_bf16_f32
__device__ __forceinline__ unsigned cvtpk(float lo, float hi) {
  __hip_bfloat162 t = __float22bfloat162_rn(float2{lo, hi});
  return *reinterpret_cast<unsigned*>(&t);
}

__device__ __forceinline__ short8 cvt8(f32x4 a, f32x4 b) {
  uint4_ u;
  u[0] = cvtpk(a[0], a[1]);
  u[1] = cvtpk(a[2], a[3]);
  u[2] = cvtpk(b[0], b[1]);
  u[3] = cvtpk(b[2], b[3]);
  return *reinterpret_cast<short8*>(&u);
}

__device__ __forceinline__ f32x4 ld_bf4(const unsigned short* p) {
  ushort4_ u = *(const ushort4_*)p;
  f32x4 r;
  r[0] = __uint_as_float((unsigned int)u[0] << 16);
  r[1] = __uint_as_float((unsigned int)u[1] << 16);
  r[2] = __uint_as_float((unsigned int)u[2] << 16);
  r[3] = __uint_as_float((unsigned int)u[3] << 16);
  return r;
}

__device__ __forceinline__ float lrelu(float v) { return v >= 0.f ? v : 0.2f * v; }

// monotone float<->uint encoding for atomicMax on floats
__device__ __forceinline__ unsigned fenc(float f) {
  unsigned b = __float_as_uint(f);
  return (b & 0x80000000u) ? ~b : (b | 0x80000000u);
}
__device__ __forceinline__ float fdec(unsigned e) {
  return __uint_as_float((e >> 31) ? (e & 0x7fffffffu) : ~e);
}

// ---- fused prep: wt2 (bf16 W, k-tiled, chunk-swizzled) + weffb + zeroing --
// wt2 tile layout: [n][c'*8+e] holds W[kt*32 + (c'^((n>>1)&3))*8 + e][n]
// so linear global_load_lds staging yields the bank-swizzled LDS image.
__global__ __launch_bounds__(256) void k_prep(const float* __restrict__ W,
                                              const float* __restrict__ asrc,
                                              const float* __restrict__ adst,
                                              unsigned short* __restrict__ wt2,
                                              unsigned short* __restrict__ weffb,
                                              int* __restrict__ cnt,
                                              unsigned* __restrict__ maxsrcE) {
  int idx = blockIdx.x * 256 + threadIdx.x;
  if (idx < 262144) {
    int k0 = idx & 31, n = (idx >> 5) & 255, kt = (idx >> 13) & 7, r = idx >> 16;
    int cp = k0 >> 3, e = k0 & 7;
    int k0s = ((cp ^ ((n >> 1) & 3)) << 3) | e;
    wt2[idx] = f2bf(W[((size_t)(r * 256) + (kt * 32 + k0s)) * 256 + n]);
  } else if (idx < 262144 + 16384) {
    int id2 = idx - 262144;
    int k0 = id2 & 31, col = (id2 >> 5) & 63, kt = id2 >> 11;
    int q = col >> 3, j = col & 7;
    int r = q >> 1, side = q & 1;
    int f = kt * 32 + k0;
    const float* att = side ? adst : asrc;
    const float* wrow = W + ((size_t)(r * 256) + f) * 256 + j * 32;
    const float* arow = att + (r * 8 + j) * 32;
    float s = 0.f;
#pragma unroll
    for (int c = 0; c < 32; ++c) s += wrow[c] * arow[c];
    weffb[id2] = f2bf(s);
  } else if (idx < 262144 + 16384 + 160000) {
    cnt[idx - (262144 + 16384)] = 0;
  } else if (idx < 262144 + 16384 + 160000 + 64) {
    maxsrcE[idx - (262144 + 16384 + 160000)] = 0u;
  }
}

// ---- CSR build ------------------------------------------------------------
__global__ __launch_bounds__(256) void k_hist(
    const int* __restrict__ e0, const int* __restrict__ e1,
    const int* __restrict__ e2, const int* __restrict__ e3, int* __restrict__ cnt) {
  int r = blockIdx.y;
  const int* ei = (r == 0) ? e0 : (r == 1) ? e1 : (r == 2) ? e2 : e3;
  int e = blockIdx.x * 256 + threadIdx.x;
  if (e < EE) atomicAdd(&cnt[r * NN + ei[EE + e]], 1);
}

__global__ __launch_bounds__(1024) void k_scan(const int* __restrict__ cnt,
                                               int* __restrict__ rowptr,
                                               int* __restrict__ cursor) {
  int r = blockIdx.x;
  const int* c = cnt + r * NN;
  int* rp = rowptr + r * (NN + 1);
  int* cur = cursor + r * NN;
  __shared__ int part[1024];
  int t = threadIdx.x;
  const int per = 40;  // 1024*40 >= 40000
  int base = t * per;
  int sum = 0;
  for (int i = 0; i < per; ++i) { int idx = base + i; if (idx < NN) sum += c[idx]; }
  part[t] = sum;
  __syncthreads();
  for (int o = 1; o < 1024; o <<= 1) {
    int v = (t >= o) ? part[t - o] : 0;
    __syncthreads();
    part[t] += v;
    __syncthreads();
  }
  int run = part[t] - sum;  // exclusive prefix
  for (int i = 0; i < per; ++i) {
    int idx = base + i;
    if (idx < NN) { rp[idx] = run; cur[idx] = run; run += c[idx]; }
  }
  if (t == 1023) rp[NN] = part[1023];
}

__global__ __launch_bounds__(256) void k_scatter(
    const int* __restrict__ e0, const int* __restrict__ e1,
    const int* __restrict__ e2, const int* __restrict__ e3,
    int* __restrict__ cursor, int* __restrict__ adj) {
  int r = blockIdx.y;
  const int* ei = (r == 0) ? e0 : (r == 1) ? e1 : (r == 2) ? e2 : e3;
  int e = blockIdx.x * 256 + threadIdx.x;
  if (e < EE) {
    int s = ei[e], d = ei[EE + e];
    int pos = atomicAdd(&cursor[r * NN + d], 1);
    adj[(size_t)r * EE + pos] = s;
  }
}

// ---- fused GEMM: hbi[r][n][g][256] = bf16(x @ W), BK=64 -------------------
// plus (r != 2): alpf[t][q][n][h][g] logits and maxsrcE atomic column maxes
__global__ __launch_bounds__(256) void k_gemmb8(
    const float* __restrict__ x0, const float* __restrict__ x1, const float* __restrict__ x2,
    const float* __restrict__ x3, const float* __restrict__ x4, const float* __restrict__ x5,
    const unsigned short* __restrict__ wt2, const unsigned short* __restrict__ weffb,
    unsigned short* __restrict__ hbi, float* __restrict__ alpf,
    unsigned* __restrict__ maxsrcE) {
  __shared__ __attribute__((aligned(16))) unsigned short A0lds[64][40];
  __shared__ __attribute__((aligned(16))) unsigned short A1lds[64][40];
  __shared__ __attribute__((aligned(16))) unsigned short B0lds[256][32];
  __shared__ __attribute__((aligned(16))) unsigned short B1lds[256][32];
  const int srct[4] = {0, 1, 0, 2};
  int y = blockIdx.y;  // g*4 + r
  int g = y >> 2, r = y & 3;
  int ty = srct[r];
  int t6 = g * 3 + ty;
  const float* xp;
  switch (t6) { case 0: xp = x0; break; case 1: xp = x1; break; case 2: xp = x2; break;
                case 3: xp = x3; break; case 4: xp = x4; break; default: xp = x5; break; }
  const unsigned short* wtp = wt2 + (size_t)r * (8 * 256 * 32);
  int tid = threadIdx.x;
  int wave = tid >> 6, lane = tid & 63;
  int l15 = lane & 15, l16 = lane >> 4;
  int row0 = blockIdx.x * 64;
  f32x4 acc[4][4] = {};
  f32x4 lacc[4] = {};
  bool dolog = (r != 2);
  int lcol = wave * 16 + l15;
  int ar = tid >> 2, ac = (tid & 3) * 16;  // 16 floats per thread per kstep
  const float* aglob = xp + (size_t)(row0 + ar) * 256 + ac;
  unsigned short* l0b = &B0lds[0][0];
  unsigned short* l1b = &B1lds[0][0];
  for (int ks = 0; ks < 4; ++ks) {
    // ---- B staging: direct global->LDS (wt2 pre-swizzled, LDS linear) ----
    const unsigned short* b0 = wtp + (2 * ks) * 8192;
    const unsigned short* b1 = wtp + (2 * ks + 1) * 8192;
#pragma unroll
    for (int i = 0; i < 4; ++i) {
      int gofs = (tid + 256 * i) * 8;             // per-lane source element
      int lofs = (wave * 64 + i * 256) * 8;       // wave-uniform LDS base
      __builtin_amdgcn_global_load_lds(
          (const __attribute__((address_space(1))) void*)(b0 + gofs),
          (__attribute__((address_space(3))) void*)(l0b + lofs), 16, 0, 0);
      __builtin_amdgcn_global_load_lds(
          (const __attribute__((address_space(1))) void*)(b1 + gofs),
          (__attribute__((address_space(3))) void*)(l1b + lofs), 16, 0, 0);
    }
    // ---- A staging: f32 read + packed cvt + ds_write ----
    f32x4 a0 = *(const f32x4*)(aglob + ks * 64);
    f32x4 a1 = *(const f32x4*)(aglob + ks * 64 + 4);
    f32x4 a2 = *(const f32x4*)(aglob + ks * 64 + 8);
    f32x4 a3 = *(const f32x4*)(aglob + ks * 64 + 12);
    if (ac < 32) {
      *(short8*)(&A0lds[ar][ac]) = cvt8(a0, a1);
      *(short8*)(&A0lds[ar][ac + 8]) = cvt8(a2, a3);
    } else {
      *(short8*)(&A1lds[ar][ac - 32]) = cvt8(a0, a1);
      *(short8*)(&A1lds[ar][ac - 24]) = cvt8(a2, a3);
    }
    __syncthreads();
#pragma unroll
    for (int kk = 0; kk < 2; ++kk) {
      short8 af[4], bf[4];
#pragma unroll
      for (int mt = 0; mt < 4; ++mt)
        af[mt] = kk ? *(const short8*)(&A1lds[mt * 16 + l15][l16 * 8])
                    : *(const short8*)(&A0lds[mt * 16 + l15][l16 * 8]);
#pragma unroll
      for (int nt = 0; nt < 4; ++nt) {
        int sn = wave * 64 + nt * 16 + l15;
        int cs = (l16 ^ ((sn >> 1) & 3)) * 8;     // bank swizzle (matches wt2)
        bf[nt] = kk ? *(const short8*)(&B1lds[sn][cs])
                    : *(const short8*)(&B0lds[sn][cs]);
      }
#pragma unroll
      for (int mt = 0; mt < 4; ++mt)
#pragma unroll
        for (int nt = 0; nt < 4; ++nt)
          acc[mt][nt] = __builtin_amdgcn_mfma_f32_16x16x32_bf16(af[mt], bf[nt], acc[mt][nt], 0, 0, 0);
      if (dolog) {
        short8 lb = *(const short8*)(weffb + (2 * ks + kk) * 2048 + lcol * 32 + l16 * 8);
#pragma unroll
        for (int mt = 0; mt < 4; ++mt)
          lacc[mt] = __builtin_amdgcn_mfma_f32_16x16x32_bf16(af[mt], lb, lacc[mt], 0, 0, 0);
      }
    }
    __syncthreads();
  }
#pragma unroll
  for (int mt = 0; mt < 4; ++mt)
#pragma unroll
    for (int nt = 0; nt < 4; ++nt)
#pragma unroll
      for (int rr = 0; rr < 4; ++rr) {
        int row = row0 + mt * 16 + l16 * 4 + rr;
        hbi[((size_t)(r * NN + row) * 2 + g) * 256 + wave * 64 + nt * 16 + l15] =
            f2bf(acc[mt][nt][rr]);
      }
  if (dolog) {
    int q = lcol >> 3, jj = lcol & 7;
#pragma unroll
    for (int mt = 0; mt < 4; ++mt)
#pragma unroll
      for (int rr = 0; rr < 4; ++rr) {
        int row = row0 + mt * 16 + l16 * 4 + rr;
        alpf[((size_t)(ty * 8 + q) * NN + row) * 16 + jj * 2 + g] = lacc[mt][rr];
      }
    // fused per-column max for src columns (q even, srct[q/2]==ty)
    if ((q & 1) == 0 && srct[q >> 1] == ty) {
      float m = -1e30f;
#pragma unroll
      for (int mt = 0; mt < 4; ++mt)
#pragma unroll
        for (int rr = 0; rr < 4; ++rr) m = fmaxf(m, lacc[mt][rr]);
      m = fmaxf(m, __shfl_xor(m, 16, 64));
      m = fmaxf(m, __shfl_xor(m, 32, 64));
      if (l16 == 0) atomicMax(maxsrcE + (g * 4 + (q >> 1)) * 8 + jj, fenc(m));
    }
  }
}

// ---- one-relation aggregation for BOTH graphs, 8-edge groups --------------
__device__ __forceinline__ void agg_one2(
    int r, int d, int lane,
    const int* __restrict__ rowptr4, const int* __restrict__ adj4,
    const float* __restrict__ alpf, const unsigned short* __restrict__ hbi,
    const unsigned* __restrict__ maxsrcE, f32x4& o0, f32x4& o1) {
  const int srct[4] = {0, 1, 0, 2};
  const int dstt[4] = {1, 0, 2, 0};
  int h = lane >> 3, e8 = lane & 7, ob = lane & 56;
  const int* rowptr = rowptr4 + r * (NN + 1);
  const int* adj = adj4 + (size_t)r * EE;
  const float* asb = alpf + ((size_t)(srct[r] * 8 + 2 * r) * NN) * 16;
  const float* adb = alpf + ((size_t)(dstt[r] * 8 + 2 * r + 1) * NN) * 16;
  const unsigned short* hbr = hbi + (size_t)(r * NN) * 512;

  int beg = rowptr[d], end = rowptr[d + 1];
  float2 adp = *(const float2*)(adb + (size_t)d * 16 + h * 2);
  float adst0 = adp.x, adst1 = adp.y;
  float ub0 = lrelu(fdec(maxsrcE[r * 8 + h]) + adst0);   // exact segment ub
  float ub1 = lrelu(fdec(maxsrcE[(4 + r) * 8 + h]) + adst1);
  float2 asp = *(const float2*)(asb + (size_t)d * 16 + h * 2);
  float ws0 = __expf(lrelu(asp.x + adst0) - ub0);
  float ws1 = __expf(lrelu(asp.y + adst1) - ub1);
  float ssum0 = (e8 == 0) ? ws0 : 0.0f;
  float ssum1 = (e8 == 0) ? ws1 : 0.0f;
  const unsigned short* selfrow = hbr + (size_t)d * 512;
  f32x4 hv0 = ld_bf4(selfrow + lane * 4);
  f32x4 hv1 = ld_bf4(selfrow + 256 + lane * 4);
  f32x4 acc0, acc1;
#pragma unroll
  for (int i = 0; i < 4; ++i) { acc0[i] = ws0 * hv0[i]; acc1[i] = ws1 * hv1[i]; }

  for (int j0 = beg; j0 < end; j0 += 8) {
    int j = j0 + e8;
    bool valid = j < end;
    int s = valid ? adj[j] : d;
    float2 lp = *(const float2*)(asb + (size_t)s * 16 + h * 2);
    float w0 = valid ? __expf(lrelu(lp.x + adst0) - ub0) : 0.f;
    float w1 = valid ? __expf(lrelu(lp.y + adst1) - ub1) : 0.f;
    ssum0 += w0;
    ssum1 += w1;
#pragma unroll
    for (int e2 = 0; e2 < 8; ++e2) {
      int se = __shfl(s, ob + e2, 64);
      float w0e = __shfl(w0, ob + e2, 64);
      float w1e = __shfl(w1, ob + e2, 64);
      const unsigned short* row = hbr + (size_t)se * 512;
      f32x4 g0 = ld_bf4(row + lane * 4);
      f32x4 g1 = ld_bf4(row + 256 + lane * 4);
#pragma unroll
      for (int i = 0; i < 4; ++i) { acc0[i] += w0e * g0[i]; acc1[i] += w1e * g1[i]; }
    }
  }
  ssum0 += __shfl_xor(ssum0, 1, 64);
  ssum0 += __shfl_xor(ssum0, 2, 64);
  ssum0 += __shfl_xor(ssum0, 4, 64);
  ssum1 += __shfl_xor(ssum1, 1, 64);
  ssum1 += __shfl_xor(ssum1, 2, 64);
  ssum1 += __shfl_xor(ssum1, 4, 64);
  float i0 = 1.f / ssum0, i1 = 1.f / ssum1;
#pragma unroll
  for (int i = 0; i < 4; ++i) { o0[i] = acc0[i] * i0; o1[i] = acc1[i] * i1; }
}

// ---- per-relation aggregation dispatch (L3 working set ~46 MB) ------------
// mode 0: write res (+bias). mode 1: write res (+bias), cached (re-read).
// mode 2: out = 0.5*(prev + res(+bias)).
__global__ __launch_bounds__(256) void k_aggr(
    const int* __restrict__ rowptr4, const int* __restrict__ adj4,
    const float* __restrict__ alpf, const unsigned short* __restrict__ hbi,
    const float* __restrict__ bias, const unsigned* __restrict__ maxsrcE,
    float* __restrict__ out, int r, int sec, int mode) {
  int wave = threadIdx.x >> 6, lane = threadIdx.x & 63;
  int d = blockIdx.x * 4 + wave;
  f32x4 o0, o1;
  agg_one2(r, d, lane, rowptr4, adj4, alpf, hbi, maxsrcE, o0, o1);
  f32x4 bv = *(const f32x4*)(bias + r * 256 + lane * 4);
  f32x4 res0, res1;
#pragma unroll
  for (int i = 0; i < 4; ++i) { res0[i] = o0[i] + bv[i]; res1[i] = o1[i] + bv[i]; }
  float* p0 = out + ((size_t)(0 + sec) * NN + d) * 256 + lane * 4;
  float* p1 = out + ((size_t)(3 + sec) * NN + d) * 256 + lane * 4;
  if (mode == 0) {
    __builtin_nontemporal_store(res0, (f32x4*)p0);
    __builtin_nontemporal_store(res1, (f32x4*)p1);
  } else if (mode == 1) {
    *(f32x4*)p0 = res0;
    *(f32x4*)p1 = res1;
  } else {
    f32x4 q0 = *(const f32x4*)p0;
    f32x4 q1 = *(const f32x4*)p1;
#pragma unroll
    for (int i = 0; i < 4; ++i) {
      res0[i] = 0.5f * (q0[i] + res0[i]);
      res1[i] = 0.5f * (q1[i] + res1[i]);
    }
    __builtin_nontemporal_store(res0, (f32x4*)p0);
    __builtin_nontemporal_store(res1, (f32x4*)p1);
  }
}

extern "C" void kernel_launch(void* const* d_in, const int* in_sizes, int n_in,
                              void* d_out, int out_size, void* d_ws, size_t ws_size,
                              hipStream_t stream) {
  (void)in_sizes; (void)n_in; (void)out_size; (void)ws_size;
  const float* x[6];
  for (int i = 0; i < 6; ++i) x[i] = (const float*)d_in[i];
  const float* W = (const float*)d_in[6];
  const float* att_src = (const float*)d_in[7];
  const float* att_dst = (const float*)d_in[8];
  const float* bias = (const float*)d_in[9];
  const int* ei[4] = {(const int*)d_in[10], (const int*)d_in[11],
                      (const int*)d_in[12], (const int*)d_in[13]};
  float* out = (float*)d_out;

  char* ws = (char*)d_ws;
  size_t off = 0;
  auto take = [&](size_t bytes) -> char* {
    char* p = ws + off;
    off += (bytes + 255) & ~(size_t)255;
    return p;
  };
  unsigned short* hbi = (unsigned short*)take(8ull * NN * 256 * 2);   // 163.8 MB
  float* alpf = (float*)take(3ull * 8 * NN * 16 * 4);                 // 61.4 MB
  unsigned short* wt2 = (unsigned short*)take(4ull * 8 * 256 * 32 * 2);
  unsigned short* weffb = (unsigned short*)take(8ull * 64 * 32 * 2);
  int* cnt = (int*)take(4ull * NN * 4);
  int* rowptr = (int*)take(4ull * (NN + 1) * 4);
  int* cursor = (int*)take(4ull * NN * 4);
  int* adj = (int*)take(4ull * EE * 4);
  unsigned* maxsrcE = (unsigned*)take(64ull * 4);

  k_prep<<<dim3(1714), 256, 0, stream>>>(W, att_src, att_dst, wt2, weffb, cnt, maxsrcE);
  k_hist<<<dim3((EE + 255) / 256, 4), 256, 0, stream>>>(ei[0], ei[1], ei[2], ei[3], cnt);
  k_scan<<<dim3(4), 1024, 0, stream>>>(cnt, rowptr, cursor);
  k_scatter<<<dim3((EE + 255) / 256, 4), 256, 0, stream>>>(ei[0], ei[1], ei[2], ei[3], cursor, adj);
  k_gemmb8<<<dim3(625, 8), 256, 0, stream>>>(x[0], x[1], x[2], x[3], x[4], x[5],
                                             wt2, weffb, hbi, alpf, maxsrcE);
  // per-relation agg: each dispatch's random working set (~46 MB) fits L3
  k_aggr<<<dim3(10000), 256, 0, stream>>>(rowptr, adj, alpf, hbi, bias, maxsrcE, out, 1, 0, 1);
  k_aggr<<<dim3(10000), 256, 0, stream>>>(rowptr, adj, alpf, hbi, bias, maxsrcE, out, 3, 0, 2);
  k_aggr<<<dim3(10000), 256, 0, stream>>>(rowptr, adj, alpf, hbi, bias, maxsrcE, out, 0, 1, 0);
  k_aggr<<<dim3(10000), 256, 0, stream>>>(rowptr, adj, alpf, hbi, bias, maxsrcE, out, 2, 2, 0);
}